// Round 6
// baseline (362.588 us; speedup 1.0000x reference)
//
#include <hip/hip_runtime.h>
#include <math.h>

#define BB 4
#define CC 64
#define OO 64
#define HH 128
#define WWD 128
#define HWP (HH*WWD)   // 16384

typedef short bf16x8 __attribute__((ext_vector_type(8)));
typedef float f32x4  __attribute__((ext_vector_type(4)));
typedef float f32x2  __attribute__((ext_vector_type(2)));

__device__ __forceinline__ unsigned short bf16_rne(float f) {
    unsigned u = __float_as_uint(f);
    u += 0x7fffu + ((u >> 16) & 1u);
    return (unsigned short)(u >> 16);
}
__device__ __forceinline__ float bf16_tof(unsigned short h) {
    return __uint_as_float((unsigned)h << 16);
}

// ---------------------------------------------------------------------------
// Forced VMEM: inline-asm loads (saddr form: SGPR base + 32b voffset).
// Opaque to the compiler's waitcnt pass -> WE own vmcnt for these.
// ---------------------------------------------------------------------------
__device__ __forceinline__ void gload2s(f32x2& d, unsigned voff, const float* sbase) {
    asm volatile("global_load_dwordx2 %0, %1, %2"
                 : "=v"(d) : "v"(voff), "s"(sbase));
}
__device__ __forceinline__ void gloadws(bf16x8& d, unsigned voff, const unsigned short* sbase) {
    asm volatile("global_load_dwordx4 %0, %1, %2"
                 : "=v"(d) : "v"(voff), "s"(sbase));
}
#define SB() __builtin_amdgcn_sched_barrier(0)
#define WAITVM_(n) asm volatile("s_waitcnt vmcnt(" #n ")")
#define WAITVM(n) WAITVM_(n)

// ---------------------------------------------------------------------------
// Kernel 1: W[o][c][3][3] fp32 -> Whi/Wlo[k][o][c] bf16 (hi/lo split) for
// both layers. grid: 288 x 256 = 73728 = 2 * 64*64*9
// ---------------------------------------------------------------------------
__global__ __launch_bounds__(256) void wtrans_kernel(
    const float* __restrict__ W1, const float* __restrict__ W2,
    unsigned short* __restrict__ Wh1, unsigned short* __restrict__ Wl1,
    unsigned short* __restrict__ Wh2, unsigned short* __restrict__ Wl2)
{
    int idx = blockIdx.x * 256 + threadIdx.x;
    const int n = OO * CC * 9;           // 36864
    const float* src;
    unsigned short *dh, *dl;
    if (idx >= n) { src = W2; dh = Wh2; dl = Wl2; idx -= n; }
    else          { src = W1; dh = Wh1; dl = Wl1; }
    int c = idx & 63;
    int o = (idx >> 6) & 63;
    int k = idx >> 12;
    float w = src[(o * CC + c) * 9 + k];
    unsigned short hi = bf16_rne(w);
    unsigned short lo = bf16_rne(w - bf16_tof(hi));
    dh[idx] = hi;
    dl[idx] = lo;
}

// ---------------------------------------------------------------------------
// Per-tap bilinear coordinates. ALL variants load x-adjacent f32 PAIRS
// (the x-clamp at 127 is folded into the weights), so gather storage is a
// uniform f32x2[8] (+[8] for the second row when DY!=0).
// ---------------------------------------------------------------------------
struct TapC {
    float w00, w01, w10, w11;
    int off0, off1;           // element offsets of top/bottom rows
};

template<int DY, int DX>
__device__ __forceinline__ TapC mk_coords(int y, int xg, float fy, float fx,
                                          float rh, float rw)
{
    TapC C; C.w00 = C.w01 = C.w10 = C.w11 = 0.f; C.off0 = C.off1 = 0;
    if (DY == 0 && DX == 0) {          // center: exact passthrough via 1/0 wts
        int ix = min(xg, WWD - 2);
        C.w00 = 1.f; C.w01 = 0.f;
        if (xg == WWD - 1) { C.w00 = 0.f; C.w01 = 1.f; }
        C.off0 = y * WWD + ix;
    } else if (DY == 0) {              // row-edge: ty == 0 exactly
        float xs = fx + (float)DX * rw;
        float x0f = floorf(xs);
        float tx = xs - x0f;
        int ix0 = min(max((int)x0f, 0), WWD - 1);
        int ix0c = min(ix0, WWD - 2);
        C.w00 = 1.f - tx; C.w01 = tx;
        if (ix0 == WWD - 1) { C.w01 += C.w00; C.w00 = 0.f; }
        C.off0 = y * WWD + ix0c;
    } else if (DX == 0) {              // col-edge: tx == 0 exactly
        float ys = fy + (float)DY * rh;
        float y0f = floorf(ys);
        float ty = ys - y0f;
        int iy0 = min(max((int)y0f, 0), HH - 1);
        int iy1 = min(iy0 + 1, HH - 1);
        int ix = min(xg, WWD - 2);
        C.w00 = 1.f - ty; C.w10 = ty; C.w01 = 0.f; C.w11 = 0.f;
        if (xg == WWD - 1) {
            C.w01 = C.w00; C.w11 = C.w10; C.w00 = 0.f; C.w10 = 0.f;
        }
        C.off0 = iy0 * WWD + ix;
        C.off1 = iy1 * WWD + ix;
    } else {                           // corner
        float ys = fy + (float)DY * rh;
        float xs = fx + (float)DX * rw;
        float y0f = floorf(ys), x0f = floorf(xs);
        float ty = ys - y0f, tx = xs - x0f;
        int iy0 = min(max((int)y0f, 0), HH - 1);
        int iy1 = min(iy0 + 1, HH - 1);
        int ix0 = min(max((int)x0f, 0), WWD - 1);
        int ix0c = min(ix0, WWD - 2);
        C.w00 = (1.f - ty) * (1.f - tx);
        C.w01 = (1.f - ty) * tx;
        C.w10 = ty * (1.f - tx);
        C.w11 = ty * tx;
        if (ix0 == WWD - 1) {
            C.w01 += C.w00; C.w00 = 0.f;
            C.w11 += C.w10; C.w10 = 0.f;
        }
        C.off0 = iy0 * WWD + ix0c;
        C.off1 = iy1 * WWD + ix0c;
    }
    return C;
}

// Issue forced-asm gathers for 8 channels of this lane's pixel.
// DY==0: 8 x dwordx2 (one row). DY!=0: 16 x dwordx2 (two rows).
template<int DY, int DX>
__device__ __forceinline__ void gather_asm(unsigned chanoff, const float* sbase,
                                           const TapC& C,
                                           f32x2 (&gt)[8], f32x2 (&gb)[8])
{
    unsigned v0 = chanoff + ((unsigned)C.off0 << 2);
#pragma unroll
    for (int i = 0; i < 8; ++i)
        gload2s(gt[i], v0 + (unsigned)(i * HWP * 4), sbase);
    if (DY != 0) {
        unsigned v1 = chanoff + ((unsigned)C.off1 << 2);
#pragma unroll
        for (int i = 0; i < 8; ++i)
            gload2s(gb[i], v1 + (unsigned)(i * HWP * 4), sbase);
    }
}

// Combine gathered pairs -> bf16 hi/lo B-fragments (channels j=0..7).
template<int DY, int DX>
__device__ __forceinline__ void combine_half(
    const TapC& C, const f32x2 (&gt)[8], const f32x2 (&gb)[8],
    bf16x8& bh, bf16x8& bl)
{
    union { unsigned short h[8]; bf16x8 v; } uh, ul;
#pragma unroll
    for (int i = 0; i < 8; ++i) {
        float s;
        if (DY == 0) {
            s = C.w00 * gt[i][0] + C.w01 * gt[i][1];
        } else {
            s = C.w00 * gt[i][0] + C.w01 * gt[i][1]
              + C.w10 * gb[i][0] + C.w11 * gb[i][1];
        }
        unsigned short hs = bf16_rne(s);
        uh.h[i] = hs;
        ul.h[i] = bf16_rne(s - bf16_tof(hs));
    }
    bh = uh.v; bl = ul.v;
}

// ---------------------------------------------------------------------------
// Kernel 2: fused offsets-conv + arconv. ZERO LDS, ZERO barriers, and the
// half-tap pipeline FORCED at asm level:
//   cluster (asm loads, next stage)  ->  s_waitcnt vmcnt(N=cluster size)
//   -> sched_barrier(0) -> combine+MFMA (current stage, loaded last cluster).
// R4/R5 lesson: compiler-managed loads/waits collapse this pipeline no
// matter how it's fenced (VGPR 80/96 proved the in-flight set never
// existed). asm-volatile loads + hand-counted vmcnt are immune.
// Parity buffers gA/gB, wA/wB -- no copies of in-flight registers.
// Counted region invariant: NO compiler-generated VMEM between the prologue
// and the final vmcnt(0) (phase A drains before; epilogue starts after;
// sched_barrier(0) at every stage boundary seals it; no spills at <256 VGPR).
// mode 1: out = relu(acc + bias). mode 2: out = resid + acc + bias.
// ---------------------------------------------------------------------------
__global__ __launch_bounds__(256, 2) void arconv_kernel(
    const float*          __restrict__ xin,   // [B,C,H,W]
    const unsigned short* __restrict__ Whi,   // [9][O][C] bf16 hi
    const unsigned short* __restrict__ Wlo,   // [9][O][C] bf16 lo
    const float*          __restrict__ bias,
    const float*          __restrict__ woff,  // [2][C][3][3]
    const float*          __restrict__ boff,  // [2]
    const int* __restrict__ lo_p, const int* __restrict__ hi_p,
    const float* __restrict__ resid,
    float* __restrict__ out, int mode)
{
    int t    = threadIdx.x;
    int bid  = blockIdx.x;
    // XCD-chunked swizzle (R1: FETCH 123MB -> 9.6MB).
    int blk  = ((bid & 7) << 7) | (bid >> 3);
    int b    = blk >> 8;
    int tile = blk & 255;
    int p0   = tile * 64;
    int y    = p0 >> 7;
    int xb   = p0 & 127;

    int lane = t & 63;
    int wv   = t >> 6;
    int nidx = lane & 15;
    int quad = lane >> 4;
    int xg   = xb + wv * 16 + nidx;       // absolute x of this lane's pixel
    float fy = (float)y;
    float fx = (float)xg;

    const float* xb_ptr = xin + (size_t)b * CC * HWP;   // wave-uniform (SGPR)

    // ---- phase A: offsets conv, barrier-free (all compiler loads; fully
    //      consumed -> vmcnt drained before the counted region) ----
    float a0 = 0.f, a1 = 0.f;
    {
#pragma unroll 4
        for (int ci = 0; ci < 16; ++ci) {
            int c = quad * 16 + ci;
            const float* xc = xb_ptr + (size_t)c * HWP;
            const float* w0 = woff + c * 9;
            const float* w1 = woff + (CC + c) * 9;
#pragma unroll
            for (int ky = 0; ky < 3; ++ky) {
                int yy = y + ky - 1;
                bool yok = (yy >= 0) && (yy < HH);
#pragma unroll
                for (int kx = 0; kx < 3; ++kx) {
                    int xx = xg + kx - 1;
                    float v = 0.f;
                    if (yok && xx >= 0 && xx < WWD) v = xc[yy * WWD + xx];
                    a0 = fmaf(v, w0[ky * 3 + kx], a0);
                    a1 = fmaf(v, w1[ky * 3 + kx], a1);
                }
            }
        }
        a0 += __shfl_xor(a0, 16); a0 += __shfl_xor(a0, 32);
        a1 += __shfl_xor(a1, 16); a1 += __shfl_xor(a1, 32);
    }
    float flo = (float)lo_p[0];
    float fhi = (float)hi_p[0];
    float rh = (flo + (fhi - flo) / (1.f + expf(-(a0 + boff[0])))) * 0.5f;
    float rw = (flo + (fhi - flo) / (1.f + expf(-(a1 + boff[1])))) * 0.5f;

    // ---- counted-vmcnt tap pipeline ----
    const unsigned choff0 = (unsigned)(quad * 8 * HWP * 4);        // ks=0, bytes
    const unsigned choff1 = choff0 + (unsigned)(32 * HWP * 4);     // ks=1
    const unsigned fragbyte = (unsigned)((nidx * CC + quad * 8) * 2);

    f32x4 acc0 = {}, acc1 = {}, acc2 = {}, acc3 = {};
    f32x2 gAt[8], gAb[8];          // gather buffer A (even stages, ks=0)
    f32x2 gBt[8], gBb[8];          // gather buffer B (odd stages, ks=1)
    bf16x8 wAh[4], wAl[4];         // weight buffer A
    bf16x8 wBh[4], wBl[4];         // weight buffer B
    TapC C;

#define MFMA(a, bfr, c) __builtin_amdgcn_mfma_f32_16x16x32_bf16(a, bfr, c, 0, 0, 0)

#define LOADW(DH, DL, K, KS) do { \
        unsigned wo_ = fragbyte + (unsigned)(((K) * OO * CC + (KS) * 32) * 2); \
        gloadws(DH[0], wo_,        Whi); gloadws(DL[0], wo_,        Wlo); \
        gloadws(DH[1], wo_ + 2048, Whi); gloadws(DL[1], wo_ + 2048, Wlo); \
        gloadws(DH[2], wo_ + 4096, Whi); gloadws(DL[2], wo_ + 4096, Wlo); \
        gloadws(DH[3], wo_ + 6144, Whi); gloadws(DL[3], wo_ + 6144, Wlo); \
    } while (0)

#define MFMA_BLOCK(WH, WL, bh, bl) do { \
        acc0 = MFMA(WH[0], bh, acc0); acc0 = MFMA(WL[0], bh, acc0); acc0 = MFMA(WH[0], bl, acc0); \
        acc1 = MFMA(WH[1], bh, acc1); acc1 = MFMA(WL[1], bh, acc1); acc1 = MFMA(WH[1], bl, acc1); \
        acc2 = MFMA(WH[2], bh, acc2); acc2 = MFMA(WL[2], bh, acc2); acc2 = MFMA(WH[2], bl, acc2); \
        acc3 = MFMA(WH[3], bh, acc3); acc3 = MFMA(WL[3], bh, acc3); acc3 = MFMA(WH[3], bl, acc3); \
    } while (0)

// N1 = gathers(cur)+8 (cluster just issued for ks=1).
// N2 = gathers(next)+8, or 0 on the last stage.
#define TAP(K, DYc, DXc, NDY, NDX, N1, N2, ISLAST) \
    { \
        /* cluster: tap K ks=1 gathers + weights into B buffers */ \
        gather_asm<DYc, DXc>(choff1, xb_ptr, C, gBt, gBb); \
        LOADW(wBh, wBl, K, 1); \
        WAITVM(N1); SB(); \
        { bf16x8 bh, bl; \
          combine_half<DYc, DXc>(C, gAt, gAb, bh, bl); \
          MFMA_BLOCK(wAh, wAl, bh, bl); } \
        SB(); \
        /* cluster: tap K+1 ks=0 gathers + weights into A buffers */ \
        TapC Cn = C; \
        if (!(ISLAST)) { \
            Cn = mk_coords<NDY, NDX>(y, xg, fy, fx, rh, rw); \
            gather_asm<NDY, NDX>(choff0, xb_ptr, Cn, gAt, gAb); \
            LOADW(wAh, wAl, (K) + 1, 0); \
        } \
        WAITVM(N2); SB(); \
        { bf16x8 bh, bl; \
          combine_half<DYc, DXc>(C, gBt, gBb, bh, bl); \
          MFMA_BLOCK(wBh, wBl, bh, bl); } \
        SB(); \
        C = Cn; \
    }

    SB();   // seal phase A out of the counted region
    // prologue: tap 0 ks=0 cluster (24 loads in flight)
    C = mk_coords<-1, -1>(y, xg, fy, fx, rh, rw);
    gather_asm<-1, -1>(choff0, xb_ptr, C, gAt, gAb);
    LOADW(wAh, wAl, 0, 0);

    //   K  cur     next    N1  N2  last
    TAP(0, -1,-1,  -1, 0,  24, 24, 0)
    TAP(1, -1, 0,  -1, 1,  24, 24, 0)
    TAP(2, -1, 1,   0,-1,  24, 16, 0)
    TAP(3,  0,-1,   0, 0,  16, 16, 0)
    TAP(4,  0, 0,   0, 1,  16, 16, 0)
    TAP(5,  0, 1,   1,-1,  16, 24, 0)
    TAP(6,  1,-1,   1, 0,  24, 24, 0)
    TAP(7,  1, 0,   1, 1,  24, 24, 0)
    TAP(8,  1, 1,   0, 0,  24,  0, 1)

#undef TAP
#undef MFMA_BLOCK
#undef LOADW
#undef MFMA

    // epilogue (after vmcnt(0)): o = mt*16 + quad*4 + r, pixel = p0+wv*16+nidx
    int px = p0 + wv * 16 + nidx;
#define EPI(MT, ACCV) do { \
        _Pragma("unroll") \
        for (int r = 0; r < 4; ++r) { \
            int o = (MT) * 16 + quad * 4 + r; \
            float v = ACCV[r] + bias[o]; \
            size_t idx = (size_t)(b * OO + o) * HWP + px; \
            if (mode == 1) v = fmaxf(v, 0.f); \
            else           v += resid[idx]; \
            out[idx] = v; \
        } \
    } while (0)
    EPI(0, acc0); EPI(1, acc1); EPI(2, acc2); EPI(3, acc3);
#undef EPI
}

// ---------------------------------------------------------------------------
extern "C" void kernel_launch(void* const* d_in, const int* in_sizes, int n_in,
                              void* d_out, int out_size, void* d_ws, size_t ws_size,
                              hipStream_t stream) {
    const float* x      = (const float*)d_in[0];
    const float* w_off1 = (const float*)d_in[1];
    const float* b_off1 = (const float*)d_in[2];
    const float* W1     = (const float*)d_in[3];
    const float* b1     = (const float*)d_in[4];
    const float* w_off2 = (const float*)d_in[5];
    const float* b_off2 = (const float*)d_in[6];
    const float* W2     = (const float*)d_in[7];
    const float* b2     = (const float*)d_in[8];
    const int*   lo_p   = (const int*)d_in[10];
    const int*   hi_p   = (const int*)d_in[11];
    float* outp = (float*)d_out;

    float* wsf = (float*)d_ws;
    float* t1  = wsf;                               // B*C*HW f32
    unsigned short* Wh1 = (unsigned short*)(t1 + (size_t)BB * CC * HWP);
    unsigned short* Wl1 = Wh1 + OO * CC * 9;        // 36864 each
    unsigned short* Wh2 = Wl1 + OO * CC * 9;
    unsigned short* Wl2 = Wh2 + OO * CC * 9;

    // 1. transpose+split both weight tensors
    wtrans_kernel<<<288, 256, 0, stream>>>(W1, W2, Wh1, Wl1, Wh2, Wl2);

    // 2. layer 1: fused offsets + arconv + relu -> t1
    arconv_kernel<<<1024, 256, 0, stream>>>(x, Wh1, Wl1, b1, w_off1, b_off1,
                                            lo_p, hi_p, nullptr, t1, 1);

    // 3. layer 2: fused offsets + arconv + residual -> out
    arconv_kernel<<<1024, 256, 0, stream>>>(t1, Wh2, Wl2, b2, w_off2, b_off2,
                                            lo_p, hi_p, x, outp, 2);
}